// Round 1
// baseline (388.565 us; speedup 1.0000x reference)
//
#include <hip/hip_runtime.h>
#include <hip/hip_bf16.h>
#include <float.h>

// Problem: B=4,S=1024 -> n=4096 tokens; D=512, O=512, E=8, K=2.
// out[n] = p[n,0]*MLP_{e0}(x[n]) + p[n,1]*MLP_{e1}(x[n])
//   where (e0,e1) = top-2 experts by softmax prob (ties -> lower index),
//   and the weights are the SLOT-indexed probs p[n,0], p[n,1] (reference quirk).
// MLP_e(x) = relu(relu(relu(x@w1[e]+b1[e])@w2[e]+b2[e])@w3[e]+b3[e])

#define NTOK   4096
#define DIM    512
#define NEXP   8
#define NENT   (NTOK * 2)          // 8192 token-expert pairs
#define CAP    8704                // padded gathered-row capacity (8192 + 8*64)
#define MAXTILES 136               // sum ceil(c_e/64) <= 128 + 8

// ---- workspace layout (bytes) ----
#define META_OFF   0u          // int[64]: [0..7] counts, [8..15] cursors, [16] num_tiles, [24..31] padoff
#define TILE_E_OFF 256u        // int[256]
#define TILE_R_OFF 1280u       // int[256]
#define TOPE_OFF   4096u       // int[8192]
#define TOPW_OFF   36864u      // float[8192]
#define ETOK_OFF   69632u      // int[CAP]
#define EW_OFF     104448u     // float[CAP]
#define H1_OFF     139264u     // float[CAP*512]
#define H2_OFF     17965056u   // float[CAP*512]

// ---------------- gating: one wave per token ----------------
__global__ __launch_bounds__(64)
void gate_kernel(const float* __restrict__ x, const float* __restrict__ gw,
                 const float* __restrict__ gb,
                 int* __restrict__ top_e, float* __restrict__ top_w)
{
    int n = blockIdx.x;
    int lane = threadIdx.x;
    const float* xr = x + (size_t)n * DIM;

    float p[NEXP];
#pragma unroll
    for (int e = 0; e < NEXP; e++) p[e] = 0.f;

#pragma unroll
    for (int j = 0; j < DIM / 64; j++) {
        int k = j * 64 + lane;
        float xv = xr[k];
        const float* g = gw + (size_t)k * NEXP;
#pragma unroll
        for (int e = 0; e < NEXP; e++) p[e] += xv * g[e];
    }
#pragma unroll
    for (int e = 0; e < NEXP; e++) {
        float v = p[e];
        for (int off = 32; off; off >>= 1) v += __shfl_xor(v, off, 64);
        p[e] = v;
    }
    if (lane == 0) {
        float l[NEXP];
#pragma unroll
        for (int e = 0; e < NEXP; e++) l[e] = p[e] + gb[e];
        float m = l[0];
#pragma unroll
        for (int e = 1; e < NEXP; e++) m = fmaxf(m, l[e]);
        float ex[NEXP], s = 0.f;
#pragma unroll
        for (int e = 0; e < NEXP; e++) { ex[e] = expf(l[e] - m); s += ex[e]; }
        // top-2 (strict >, ascending scan -> lowest index wins ties, matches lax.top_k)
        int e0 = 0; float m0 = l[0];
#pragma unroll
        for (int e = 1; e < NEXP; e++) if (l[e] > m0) { m0 = l[e]; e0 = e; }
        int e1 = -1; float m1 = -FLT_MAX;
#pragma unroll
        for (int e = 0; e < NEXP; e++) if (e != e0 && l[e] > m1) { m1 = l[e]; e1 = e; }
        // slot-indexed weights (reference quirk): probs of experts 0 and 1
        float inv = 1.f / s;
        top_e[2 * n + 0] = e0;
        top_e[2 * n + 1] = e1;
        top_w[2 * n + 0] = ex[0] * inv;
        top_w[2 * n + 1] = ex[1] * inv;
    }
}

// ---------------- counts: wave-aggregated ----------------
__global__ __launch_bounds__(256)
void count_kernel(const int* __restrict__ top_e, int* __restrict__ meta)
{
    int t = blockIdx.x * 256 + threadIdx.x;   // entry index, 0..8191
    int e = top_e[t];
    int lane = threadIdx.x & 63;
#pragma unroll
    for (int ex = 0; ex < NEXP; ex++) {
        unsigned long long m = __ballot(e == ex);
        if (e == ex && (__ffsll(m) - 1) == lane)
            atomicAdd(&meta[ex], __popcll(m));
    }
}

// ---------------- scan + tile map (single thread; 8 experts) ----------------
__global__ __launch_bounds__(64)
void scan_kernel(int* __restrict__ meta, int* __restrict__ tile_e, int* __restrict__ tile_r)
{
    if (threadIdx.x == 0 && blockIdx.x == 0) {
        int off = 0, nt = 0;
        for (int e = 0; e < NEXP; e++) {
            int c = meta[e];
            meta[24 + e] = off;
            int tiles = (c + 63) >> 6;
            for (int t = 0; t < tiles; t++) { tile_e[nt] = e; tile_r[nt] = off + (t << 6); nt++; }
            off += tiles << 6;
        }
        meta[16] = nt;
        meta[17] = off;
    }
}

// ---------------- scatter tokens into per-expert gathered lists ----------------
__global__ __launch_bounds__(256)
void scatter_kernel(const int* __restrict__ top_e, const float* __restrict__ top_w,
                    int* __restrict__ meta, int* __restrict__ entry_tok,
                    float* __restrict__ entry_w)
{
    int n = blockIdx.x * 256 + threadIdx.x;   // token
    int lane = threadIdx.x & 63;
#pragma unroll
    for (int j = 0; j < 2; j++) {
        int e = top_e[2 * n + j];
        float w = top_w[2 * n + j];
        int pos = 0;
        for (int ex = 0; ex < NEXP; ex++) {
            unsigned long long m = __ballot(e == ex);
            if (e == ex) {
                int leader = __ffsll(m) - 1;
                int base = 0;
                if (lane == leader) base = atomicAdd(&meta[8 + ex], __popcll(m));
                base = __shfl(base, leader, 64);
                pos = meta[24 + ex] + base + __popcll(m & ((1ull << lane) - 1ull));
            }
        }
        entry_tok[pos] = n;
        entry_w[pos] = w;
    }
}

// ---------------- tiled fp32 GEMM over gathered rows ----------------
// LAYER 1: A = x (gathered via entry_tok), Out = h1, relu
// LAYER 2: A = h_in (dense gathered order), Out = h2, relu
// LAYER 3: A = h_in, epilogue: out[tok] += w * relu(acc + b)   (atomic)
template <int LAYER>
__global__ __launch_bounds__(256)
void gemm_layer(const float* __restrict__ A, const float* __restrict__ W,
                const float* __restrict__ Bias, float* __restrict__ Out,
                const int* __restrict__ meta, const int* __restrict__ tile_e,
                const int* __restrict__ tile_r, const int* __restrict__ entry_tok,
                const float* __restrict__ entry_w)
{
    int tile = blockIdx.y;
    if (tile >= meta[16]) return;
    int e = tile_e[tile];
    int row0 = tile_r[tile];
    int n0 = blockIdx.x * 64;

    __shared__ float As[16][68];
    __shared__ float Bs[16][68];
    __shared__ int rtok[64];

    int tid = threadIdx.x;
    if (tid < 64) rtok[tid] = entry_tok[row0 + tid];
    __syncthreads();

    const float* Wb = W + (size_t)e * DIM * DIM;

    float acc[4][4];
#pragma unroll
    for (int r = 0; r < 4; r++)
#pragma unroll
        for (int c = 0; c < 4; c++) acc[r][c] = 0.f;

    int lk = tid & 15, lr = tid >> 4;     // A-load: col-in-tile, row base
    int bn = tid & 63, bk = tid >> 6;     // B-load: col, k base
    int tx = tid & 15, ty = tid >> 4;     // compute mapping

    for (int k0 = 0; k0 < DIM; k0 += 16) {
#pragma unroll
        for (int i = 0; i < 4; i++) {
            int r = lr + 16 * i;
            float v;
            if (LAYER == 1) {
                int tok = rtok[r];
                v = (tok >= 0) ? A[(size_t)tok * DIM + k0 + lk] : 0.f;
            } else {
                v = A[(size_t)(row0 + r) * DIM + k0 + lk];
            }
            As[lk][r] = v;
        }
#pragma unroll
        for (int i = 0; i < 4; i++) {
            int kk = bk + 4 * i;
            Bs[kk][bn] = Wb[(size_t)(k0 + kk) * DIM + n0 + bn];
        }
        __syncthreads();
#pragma unroll
        for (int kk = 0; kk < 16; kk++) {
            float4 av = *(const float4*)&As[kk][ty * 4];
            float4 bv = *(const float4*)&Bs[kk][tx * 4];
            float ar[4] = {av.x, av.y, av.z, av.w};
            float bc[4] = {bv.x, bv.y, bv.z, bv.w};
#pragma unroll
            for (int r = 0; r < 4; r++)
#pragma unroll
                for (int c = 0; c < 4; c++) acc[r][c] += ar[r] * bc[c];
        }
        __syncthreads();
    }

    float4 bvec = *(const float4*)&Bias[(size_t)e * DIM + n0 + tx * 4];
    float bc[4] = {bvec.x, bvec.y, bvec.z, bvec.w};

    if (LAYER < 3) {
#pragma unroll
        for (int r = 0; r < 4; r++) {
            int row = row0 + ty * 4 + r;
            float4 o;
            o.x = fmaxf(acc[r][0] + bc[0], 0.f);
            o.y = fmaxf(acc[r][1] + bc[1], 0.f);
            o.z = fmaxf(acc[r][2] + bc[2], 0.f);
            o.w = fmaxf(acc[r][3] + bc[3], 0.f);
            *(float4*)&Out[(size_t)row * DIM + n0 + tx * 4] = o;
        }
    } else {
#pragma unroll
        for (int r = 0; r < 4; r++) {
            int lrow = ty * 4 + r;
            int tok = rtok[lrow];
            if (tok >= 0) {
                float w = entry_w[row0 + lrow];
#pragma unroll
                for (int c = 0; c < 4; c++) {
                    float y = fmaxf(acc[r][c] + bc[c], 0.f);
                    atomicAdd(&Out[(size_t)tok * DIM + n0 + tx * 4 + c], w * y);
                }
            }
        }
    }
}

extern "C" void kernel_launch(void* const* d_in, const int* in_sizes, int n_in,
                              void* d_out, int out_size, void* d_ws, size_t ws_size,
                              hipStream_t stream)
{
    const float* x      = (const float*)d_in[0];
    const float* gate_w = (const float*)d_in[1];
    const float* gate_b = (const float*)d_in[2];
    const float* w1     = (const float*)d_in[3];
    const float* b1     = (const float*)d_in[4];
    const float* w2     = (const float*)d_in[5];
    const float* b2     = (const float*)d_in[6];
    const float* w3     = (const float*)d_in[7];
    const float* b3     = (const float*)d_in[8];
    float* out = (float*)d_out;

    char* ws = (char*)d_ws;
    int*   meta      = (int*)(ws + META_OFF);
    int*   tile_e    = (int*)(ws + TILE_E_OFF);
    int*   tile_r    = (int*)(ws + TILE_R_OFF);
    int*   top_e     = (int*)(ws + TOPE_OFF);
    float* top_w     = (float*)(ws + TOPW_OFF);
    int*   entry_tok = (int*)(ws + ETOK_OFF);
    float* entry_w   = (float*)(ws + EW_OFF);
    float* h1        = (float*)(ws + H1_OFF);
    float* h2        = (float*)(ws + H2_OFF);

    hipMemsetAsync(meta, 0, 256, stream);
    hipMemsetAsync(entry_tok, 0xFF, CAP * sizeof(int), stream);
    hipMemsetAsync(out, 0, (size_t)out_size * sizeof(float), stream);

    gate_kernel<<<NTOK, 64, 0, stream>>>(x, gate_w, gate_b, top_e, top_w);
    count_kernel<<<NENT / 256, 256, 0, stream>>>(top_e, meta);
    scan_kernel<<<1, 64, 0, stream>>>(meta, tile_e, tile_r);
    scatter_kernel<<<NTOK / 256, 256, 0, stream>>>(top_e, top_w, meta, entry_tok, entry_w);

    dim3 grid(DIM / 64, MAXTILES);
    gemm_layer<1><<<grid, 256, 0, stream>>>(x,  w1, b1, h1,  meta, tile_e, tile_r, entry_tok, entry_w);
    gemm_layer<2><<<grid, 256, 0, stream>>>(h1, w2, b2, h2,  meta, tile_e, tile_r, entry_tok, entry_w);
    gemm_layer<3><<<grid, 256, 0, stream>>>(h2, w3, b3, out, meta, tile_e, tile_r, entry_tok, entry_w);
}

// Round 2
// 201.065 us; speedup vs baseline: 1.9325x; 1.9325x over previous
//
#include <hip/hip_runtime.h>
#include <hip/hip_bf16.h>
#include <float.h>

// MoE: n=4096 tokens, D=O=512, E=8, K=2 (top-2), 3-layer ReLU MLP per expert.
// out[n] = p[n,0]*MLP_{e0}(x[n]) + p[n,1]*MLP_{e1}(x[n])   (slot-indexed probs quirk)
// GEMM core: fp16 MFMA 16x16x32, fp32 accumulate, 128x128 tiles, BK=32,
// global_load_lds(16B) staging into group-major LDS (conflict-free ds_read_b128).

#define NTOK   4096
#define DIM    512
#define NEXP   8
#define NENT   (NTOK * 2)
#define CAP    9216                // 8192 + 8*128 pad rows
#define MAXT   72                  // sum ceil(c_e/128) <= 64+8
#define BM 128
#define BN 128
#define BK 32

typedef _Float16 half8 __attribute__((ext_vector_type(8)));
typedef float    f32x4 __attribute__((ext_vector_type(4)));

// ---- workspace layout (bytes) ----
#define META_OFF   0u          // int[64]: [0..7] counts, [8..15] cursors, [16] ntiles, [24..31] padded offs
#define TILE_E_OFF 1024u       // int[256]
#define TILE_R_OFF 2048u       // int[256]
#define TOPE_OFF   4096u       // int[8192]
#define TOPW_OFF   36864u      // float[8192]
#define POS_OFF    69632u      // int[8192]
#define ETOK_OFF   102400u     // int[CAP]
#define XH_OFF     176128u     // f16[4096*512]  = 4 MB
#define WT_OFF     4370432u    // f16[3*8*512*512] = 12.6 MB (transposed [l][e][n][k])
#define H1_OFF     16953344u   // f16[CAP*512]
#define H2_OFF     26390528u   // f16[CAP*512]
// total ~35.8 MB

#define GLOAD_LDS16(g, s) \
    __builtin_amdgcn_global_load_lds((const __attribute__((address_space(1))) void*)(g), \
                                     (__attribute__((address_space(3))) void*)(s), 16, 0, 0)

// ---------------- gating: one wave per token (fp32, exact) ----------------
__global__ __launch_bounds__(64)
void gate_kernel(const float* __restrict__ x, const float* __restrict__ gw,
                 const float* __restrict__ gb,
                 int* __restrict__ top_e, float* __restrict__ top_w)
{
    int n = blockIdx.x;
    int lane = threadIdx.x;
    const float* xr = x + (size_t)n * DIM;

    float p[NEXP];
#pragma unroll
    for (int e = 0; e < NEXP; e++) p[e] = 0.f;
#pragma unroll
    for (int j = 0; j < DIM / 64; j++) {
        int k = j * 64 + lane;
        float xv = xr[k];
        const float* g = gw + (size_t)k * NEXP;
#pragma unroll
        for (int e = 0; e < NEXP; e++) p[e] += xv * g[e];
    }
#pragma unroll
    for (int e = 0; e < NEXP; e++) {
        float v = p[e];
        for (int off = 32; off; off >>= 1) v += __shfl_xor(v, off, 64);
        p[e] = v;
    }
    if (lane == 0) {
        float l[NEXP];
#pragma unroll
        for (int e = 0; e < NEXP; e++) l[e] = p[e] + gb[e];
        float m = l[0];
#pragma unroll
        for (int e = 1; e < NEXP; e++) m = fmaxf(m, l[e]);
        float ex[NEXP], s = 0.f;
#pragma unroll
        for (int e = 0; e < NEXP; e++) { ex[e] = expf(l[e] - m); s += ex[e]; }
        int e0 = 0; float m0 = l[0];
#pragma unroll
        for (int e = 1; e < NEXP; e++) if (l[e] > m0) { m0 = l[e]; e0 = e; }
        int e1 = -1; float m1 = -FLT_MAX;
#pragma unroll
        for (int e = 0; e < NEXP; e++) if (e != e0 && l[e] > m1) { m1 = l[e]; e1 = e; }
        float inv = 1.f / s;
        top_e[2 * n + 0] = e0;
        top_e[2 * n + 1] = e1;
        top_w[2 * n + 0] = ex[0] * inv;   // slot-indexed probs (reference quirk)
        top_w[2 * n + 1] = ex[1] * inv;
    }
}

// ---------------- counts: wave-aggregated ----------------
__global__ __launch_bounds__(256)
void count_kernel(const int* __restrict__ top_e, int* __restrict__ meta)
{
    int t = blockIdx.x * 256 + threadIdx.x;
    int e = top_e[t];
    int lane = threadIdx.x & 63;
#pragma unroll
    for (int ex = 0; ex < NEXP; ex++) {
        unsigned long long m = __ballot(e == ex);
        if (e == ex && (__ffsll(m) - 1) == lane)
            atomicAdd(&meta[ex], __popcll(m));
    }
}

// ---------------- scan + tile map (128-row tiles) ----------------
__global__ __launch_bounds__(64)
void scan_kernel(int* __restrict__ meta, int* __restrict__ tile_e, int* __restrict__ tile_r)
{
    if (threadIdx.x == 0 && blockIdx.x == 0) {
        int off = 0, nt = 0;
        for (int e = 0; e < NEXP; e++) {
            int c = meta[e];
            meta[24 + e] = off;
            int tiles = (c + 127) >> 7;
            for (int t = 0; t < tiles; t++) { tile_e[nt] = e; tile_r[nt] = off + (t << 7); nt++; }
            off += tiles << 7;
        }
        meta[16] = nt;
        meta[17] = off;
    }
}

// ---------------- scatter tokens into per-expert gathered lists ----------------
__global__ __launch_bounds__(256)
void scatter_kernel(const int* __restrict__ top_e, int* __restrict__ meta,
                    int* __restrict__ entry_tok, int* __restrict__ pos_of)
{
    int n = blockIdx.x * 256 + threadIdx.x;
    int lane = threadIdx.x & 63;
#pragma unroll
    for (int j = 0; j < 2; j++) {
        int e = top_e[2 * n + j];
        int pos = 0;
        for (int ex = 0; ex < NEXP; ex++) {
            unsigned long long m = __ballot(e == ex);
            if (e == ex) {
                int leader = __ffsll(m) - 1;
                int base = 0;
                if (lane == leader) base = atomicAdd(&meta[8 + ex], __popcll(m));
                base = __shfl(base, leader, 64);
                pos = meta[24 + ex] + base + __popcll(m & ((1ull << lane) - 1ull));
            }
        }
        entry_tok[pos] = n;
        pos_of[2 * n + j] = pos;
    }
}

// ---------------- convert x -> fp16 ----------------
__global__ __launch_bounds__(256)
void convert_x(const float* __restrict__ x, _Float16* __restrict__ xh)
{
    int i = blockIdx.x * 256 + threadIdx.x;   // 8 elems each
    const float4* src = (const float4*)(x) + 2 * i;
    float4 a = src[0], b = src[1];
    half8 h = { (_Float16)a.x, (_Float16)a.y, (_Float16)a.z, (_Float16)a.w,
                (_Float16)b.x, (_Float16)b.y, (_Float16)b.z, (_Float16)b.w };
    *(half8*)(xh + (size_t)i * 8) = h;
}

// ---------------- transpose+convert weights: W[l][e][k][n] -> Wt[l][e][n][k] fp16 ----------------
__global__ __launch_bounds__(256)
void transpose_w(const float* __restrict__ W1, const float* __restrict__ W2,
                 const float* __restrict__ W3, _Float16* __restrict__ Wt)
{
    __shared__ float t[32][33];
    int mat = blockIdx.z;
    const float* src = (mat < 8) ? W1 + (size_t)mat * DIM * DIM
                     : (mat < 16) ? W2 + (size_t)(mat - 8) * DIM * DIM
                                  : W3 + (size_t)(mat - 16) * DIM * DIM;
    _Float16* dst = Wt + (size_t)mat * DIM * DIM;
    int tx = threadIdx.x & 31, ty = threadIdx.x >> 5;   // 32 x 8
    int x0 = blockIdx.x * 32, y0 = blockIdx.y * 32;     // x: n, y: k
#pragma unroll
    for (int j = 0; j < 4; j++)
        t[ty + 8 * j][tx] = src[(size_t)(y0 + ty + 8 * j) * DIM + x0 + tx];
    __syncthreads();
#pragma unroll
    for (int j = 0; j < 4; j++)
        dst[(size_t)(x0 + ty + 8 * j) * DIM + y0 + tx] = (_Float16)t[tx][ty + 8 * j];
}

// ---------------- fp16 MFMA GEMM over gathered rows ----------------
// GATHER=1: A rows via entry_tok (layer 1); else contiguous gathered order.
// Out[row][col] = f16(relu(acc + bias[col]))
template <int GATHER>
__global__ __launch_bounds__(256)
void gemm_mfma(const _Float16* __restrict__ A, const _Float16* __restrict__ Wt,
               const float* __restrict__ Bias, _Float16* __restrict__ Out,
               const int* __restrict__ meta, const int* __restrict__ tile_e,
               const int* __restrict__ tile_r, const int* __restrict__ entry_tok)
{
    int tile = blockIdx.y;
    if (tile >= meta[16]) return;
    int e = tile_e[tile];
    int row0 = tile_r[tile];
    int n0 = blockIdx.x * BN;

    // group-major LDS: group g (16 rows x 32 k) occupies 1024 B; within group,
    // byte offset l*16 holds row (l&15), k-chunk (l>>4)*8 — matches both the
    // global_load_lds lane->dest map and the MFMA fragment read (linear l*16).
    __shared__ _Float16 sA[BM * BK];
    __shared__ _Float16 sB[BN * BK];
    __shared__ int rtok[BM];

    int tid = threadIdx.x;
    int w = tid >> 6, l = tid & 63;
    int rlo = l & 15, kc = l >> 4;

    if (GATHER) {
        if (tid < BM) {
            int t = entry_tok[row0 + tid];
            rtok[tid] = (t < 0) ? 0 : t;    // pad rows read token 0; dropped later
        }
        __syncthreads();
    }

    const _Float16* Wb = Wt + (size_t)e * DIM * DIM;

    // staging sources: wave w stages A-groups {w, w+4} and B-groups {w, w+4}
    int ar0, ar1;
    if (GATHER) { ar0 = rtok[w * 16 + rlo]; ar1 = rtok[(w + 4) * 16 + rlo]; }
    else        { ar0 = row0 + w * 16 + rlo; ar1 = row0 + (w + 4) * 16 + rlo; }
    const _Float16* asrc0 = A + (size_t)ar0 * DIM + kc * 8;
    const _Float16* asrc1 = A + (size_t)ar1 * DIM + kc * 8;
    const _Float16* bsrc0 = Wb + (size_t)(n0 + w * 16 + rlo) * DIM + kc * 8;
    const _Float16* bsrc1 = Wb + (size_t)(n0 + (w + 4) * 16 + rlo) * DIM + kc * 8;

    _Float16* sA0 = sA + w * 512;        // wave-uniform LDS dest bases
    _Float16* sA1 = sA + (w + 4) * 512;
    _Float16* sB0 = sB + w * 512;
    _Float16* sB1 = sB + (w + 4) * 512;

    int mg = (w >> 1) * 4;               // compute group bases
    int ng = (w & 1) * 4;

    f32x4 acc[4][4];
#pragma unroll
    for (int mi = 0; mi < 4; mi++)
#pragma unroll
        for (int ni = 0; ni < 4; ni++) acc[mi][ni] = (f32x4){0.f, 0.f, 0.f, 0.f};

    for (int k0 = 0; k0 < DIM; k0 += BK) {
        __syncthreads();                 // previous iter's frag reads done
        GLOAD_LDS16(asrc0 + k0, sA0);
        GLOAD_LDS16(asrc1 + k0, sA1);
        GLOAD_LDS16(bsrc0 + k0, sB0);
        GLOAD_LDS16(bsrc1 + k0, sB1);
        __syncthreads();                 // staging complete (vmcnt drained)

        half8 af[4], bf[4];
#pragma unroll
        for (int mi = 0; mi < 4; mi++) af[mi] = *(const half8*)(sA + (mg + mi) * 512 + l * 8);
#pragma unroll
        for (int ni = 0; ni < 4; ni++) bf[ni] = *(const half8*)(sB + (ng + ni) * 512 + l * 8);
#pragma unroll
        for (int mi = 0; mi < 4; mi++)
#pragma unroll
            for (int ni = 0; ni < 4; ni++)
                acc[mi][ni] = __builtin_amdgcn_mfma_f32_16x16x32_f16(af[mi], bf[ni], acc[mi][ni], 0, 0, 0);
    }

    // epilogue: C/D layout col=lane&15, row=(lane>>4)*4+reg
    int wm = (w >> 1) * 64, wn = (w & 1) * 64;
#pragma unroll
    for (int ni = 0; ni < 4; ni++) {
        int col = n0 + wn + ni * 16 + (l & 15);
        float b = Bias[e * DIM + col];
#pragma unroll
        for (int mi = 0; mi < 4; mi++) {
            int rbase = row0 + wm + mi * 16 + (l >> 4) * 4;
#pragma unroll
            for (int r = 0; r < 4; r++) {
                float v = fmaxf(acc[mi][ni][r] + b, 0.f);
                Out[(size_t)(rbase + r) * DIM + col] = (_Float16)v;
            }
        }
    }
}

// ---------------- combine: out[n] = w0*y[pos0] + w1*y[pos1] ----------------
__global__ __launch_bounds__(256)
void combine_kernel(const _Float16* __restrict__ y, const int* __restrict__ pos_of,
                    const float* __restrict__ top_w, float* __restrict__ out)
{
    int n = blockIdx.x * 4 + (threadIdx.x >> 6);
    int l = threadIdx.x & 63;
    int p0 = pos_of[2 * n], p1 = pos_of[2 * n + 1];
    float w0 = top_w[2 * n], w1 = top_w[2 * n + 1];
    half8 a = *(const half8*)(y + (size_t)p0 * DIM + l * 8);
    half8 b = *(const half8*)(y + (size_t)p1 * DIM + l * 8);
    float4 o0, o1;
    o0.x = w0 * (float)a[0] + w1 * (float)b[0];
    o0.y = w0 * (float)a[1] + w1 * (float)b[1];
    o0.z = w0 * (float)a[2] + w1 * (float)b[2];
    o0.w = w0 * (float)a[3] + w1 * (float)b[3];
    o1.x = w0 * (float)a[4] + w1 * (float)b[4];
    o1.y = w0 * (float)a[5] + w1 * (float)b[5];
    o1.z = w0 * (float)a[6] + w1 * (float)b[6];
    o1.w = w0 * (float)a[7] + w1 * (float)b[7];
    float* op = out + (size_t)n * DIM + l * 8;
    *(float4*)op = o0;
    *(float4*)(op + 4) = o1;
}

extern "C" void kernel_launch(void* const* d_in, const int* in_sizes, int n_in,
                              void* d_out, int out_size, void* d_ws, size_t ws_size,
                              hipStream_t stream)
{
    const float* x      = (const float*)d_in[0];
    const float* gate_w = (const float*)d_in[1];
    const float* gate_b = (const float*)d_in[2];
    const float* w1     = (const float*)d_in[3];
    const float* b1     = (const float*)d_in[4];
    const float* w2     = (const float*)d_in[5];
    const float* b2     = (const float*)d_in[6];
    const float* w3     = (const float*)d_in[7];
    const float* b3     = (const float*)d_in[8];
    float* out = (float*)d_out;

    char* ws = (char*)d_ws;
    int*      meta      = (int*)(ws + META_OFF);
    int*      tile_e    = (int*)(ws + TILE_E_OFF);
    int*      tile_r    = (int*)(ws + TILE_R_OFF);
    int*      top_e     = (int*)(ws + TOPE_OFF);
    float*    top_w     = (float*)(ws + TOPW_OFF);
    int*      pos_of    = (int*)(ws + POS_OFF);
    int*      entry_tok = (int*)(ws + ETOK_OFF);
    _Float16* xh        = (_Float16*)(ws + XH_OFF);
    _Float16* wt        = (_Float16*)(ws + WT_OFF);
    _Float16* h1        = (_Float16*)(ws + H1_OFF);
    _Float16* h2        = (_Float16*)(ws + H2_OFF);

    hipMemsetAsync(meta, 0, 256, stream);
    hipMemsetAsync(entry_tok, 0xFF, CAP * sizeof(int), stream);

    gate_kernel<<<NTOK, 64, 0, stream>>>(x, gate_w, gate_b, top_e, top_w);
    count_kernel<<<NENT / 256, 256, 0, stream>>>(top_e, meta);
    scan_kernel<<<1, 64, 0, stream>>>(meta, tile_e, tile_r);
    scatter_kernel<<<NTOK / 256, 256, 0, stream>>>(top_e, meta, entry_tok, pos_of);

    convert_x<<<(NTOK * DIM / 8) / 256, 256, 0, stream>>>(x, xh);
    transpose_w<<<dim3(16, 16, 24), 256, 0, stream>>>(w1, w2, w3, wt);

    _Float16* wt1 = wt;
    _Float16* wt2 = wt + (size_t)8 * DIM * DIM;
    _Float16* wt3 = wt + (size_t)16 * DIM * DIM;

    dim3 grid(DIM / BN, MAXT);
    gemm_mfma<1><<<grid, 256, 0, stream>>>(xh, wt1, b1, h1, meta, tile_e, tile_r, entry_tok);
    gemm_mfma<0><<<grid, 256, 0, stream>>>(h1, wt2, b2, h2, meta, tile_e, tile_r, entry_tok);
    gemm_mfma<0><<<grid, 256, 0, stream>>>(h2, wt3, b3, h1, meta, tile_e, tile_r, entry_tok);  // y -> h1 (reuse)

    combine_kernel<<<NTOK / 4, 256, 0, stream>>>(h1, pos_of, top_w, out);
}

// Round 3
// 195.314 us; speedup vs baseline: 1.9894x; 1.0294x over previous
//
#include <hip/hip_runtime.h>
#include <hip/hip_bf16.h>
#include <float.h>

// MoE: n=4096 tokens, D=O=512, E=8, top-2, 3-layer ReLU MLP per expert.
// out[n] = p[n,0]*MLP_{e0}(x[n]) + p[n,1]*MLP_{e1}(x[n])   (slot-indexed probs quirk)
// GEMM: fp16 MFMA 16x16x32, 64x128 tiles, BK=64, double-buffered LDS,
// prefetch-before-compute, one barrier per K-iter (latency-tolerant at ~2 blocks/CU).

#define NTOK   4096
#define DIM    512
#define NEXP   8
#define NENT   (NTOK * 2)
#define CAP    8704                // 8192 + 8*64 pad rows
#define MAXT   136                 // sum ceil(c_e/64) <= 135
#define BM 64
#define BN 128
#define BK 64
#define NIT (DIM / BK)             // 8

typedef _Float16 half8 __attribute__((ext_vector_type(8)));
typedef float    f32x4 __attribute__((ext_vector_type(4)));

// ---- workspace layout (bytes) ----
#define META_OFF   0u          // int[64]: [0..7] counts, [8..15] cursors, [16] ntiles, [24..31] padded offs
#define TILE_E_OFF 1024u       // int[160]
#define TILE_R_OFF 2048u       // int[160]
#define TOPE_OFF   4096u       // int[8192]
#define TOPW_OFF   36864u      // float[8192]
#define POS_OFF    69632u      // int[8192]
#define ETOK_OFF   102400u     // int[CAP]
#define XH_OFF     139264u     // f16[4096*512]  = 4 MB
#define WT_OFF     4333568u    // f16[24*512*512] = 12.6 MB ([l][e][n][k])
#define H1_OFF     16916480u   // f16[CAP*512] = 8.9 MB
#define H2_OFF     25829376u   // f16[CAP*512]
// total ~34.7 MB

#define GLOAD_LDS16(g, s) \
    __builtin_amdgcn_global_load_lds((const __attribute__((address_space(1))) void*)(g), \
                                     (__attribute__((address_space(3))) void*)(s), 16, 0, 0)

// ---------------- gate + convert_x + count, fused: one wave per token ----------------
__global__ __launch_bounds__(256)
void gate_kernel(const float* __restrict__ x, const float* __restrict__ gw,
                 const float* __restrict__ gb,
                 int* __restrict__ top_e, float* __restrict__ top_w,
                 _Float16* __restrict__ xh, int* __restrict__ meta)
{
    __shared__ int scnt[NEXP];
    int tid = threadIdx.x;
    if (tid < NEXP) scnt[tid] = 0;
    __syncthreads();

    int n = blockIdx.x * 4 + (tid >> 6);
    int lane = tid & 63;
    const float* xr = x + (size_t)n * DIM + lane * 8;
    float4 v0 = *(const float4*)xr;
    float4 v1 = *(const float4*)(xr + 4);
    float xv[8] = {v0.x, v0.y, v0.z, v0.w, v1.x, v1.y, v1.z, v1.w};

    half8 h = { (_Float16)xv[0], (_Float16)xv[1], (_Float16)xv[2], (_Float16)xv[3],
                (_Float16)xv[4], (_Float16)xv[5], (_Float16)xv[6], (_Float16)xv[7] };
    *(half8*)(xh + (size_t)n * DIM + lane * 8) = h;

    float p[NEXP];
#pragma unroll
    for (int e = 0; e < NEXP; e++) p[e] = 0.f;
    const float* g = gw + (size_t)lane * 64;   // rows k = lane*8 .. lane*8+7
#pragma unroll
    for (int j = 0; j < 8; j++)
#pragma unroll
        for (int e = 0; e < NEXP; e++) p[e] += xv[j] * g[j * 8 + e];
#pragma unroll
    for (int e = 0; e < NEXP; e++) {
        float v = p[e];
        for (int off = 32; off; off >>= 1) v += __shfl_xor(v, off, 64);
        p[e] = v;
    }
    if (lane == 0) {
        float l[NEXP];
#pragma unroll
        for (int e = 0; e < NEXP; e++) l[e] = p[e] + gb[e];
        float m = l[0];
#pragma unroll
        for (int e = 1; e < NEXP; e++) m = fmaxf(m, l[e]);
        float ex[NEXP], s = 0.f;
#pragma unroll
        for (int e = 0; e < NEXP; e++) { ex[e] = expf(l[e] - m); s += ex[e]; }
        int e0 = 0; float m0 = l[0];
#pragma unroll
        for (int e = 1; e < NEXP; e++) if (l[e] > m0) { m0 = l[e]; e0 = e; }
        int e1 = -1; float m1 = -FLT_MAX;
#pragma unroll
        for (int e = 0; e < NEXP; e++) if (e != e0 && l[e] > m1) { m1 = l[e]; e1 = e; }
        float inv = 1.f / s;
        top_e[2 * n + 0] = e0;
        top_e[2 * n + 1] = e1;
        top_w[2 * n + 0] = ex[0] * inv;   // slot-indexed probs (reference quirk)
        top_w[2 * n + 1] = ex[1] * inv;
        atomicAdd(&scnt[e0], 1);
        atomicAdd(&scnt[e1], 1);
    }
    __syncthreads();
    if (tid < NEXP) atomicAdd(&meta[tid], scnt[tid]);
}

// ---------------- scan + tile map (64-row tiles) ----------------
__global__ __launch_bounds__(64)
void scan_kernel(int* __restrict__ meta, int* __restrict__ tile_e, int* __restrict__ tile_r)
{
    if (threadIdx.x == 0 && blockIdx.x == 0) {
        int off = 0, nt = 0;
        for (int e = 0; e < NEXP; e++) {
            int c = meta[e];
            meta[24 + e] = off;
            int tiles = (c + 63) >> 6;
            for (int t = 0; t < tiles; t++) { tile_e[nt] = e; tile_r[nt] = off + (t << 6); nt++; }
            off += tiles << 6;
        }
        meta[16] = nt;
        meta[17] = off;
    }
}

// ---------------- scatter tokens into per-expert gathered lists ----------------
__global__ __launch_bounds__(256)
void scatter_kernel(const int* __restrict__ top_e, int* __restrict__ meta,
                    int* __restrict__ entry_tok, int* __restrict__ pos_of)
{
    int n = blockIdx.x * 256 + threadIdx.x;
    int lane = threadIdx.x & 63;
#pragma unroll
    for (int j = 0; j < 2; j++) {
        int e = top_e[2 * n + j];
        int pos = 0;
        for (int ex = 0; ex < NEXP; ex++) {
            unsigned long long m = __ballot(e == ex);
            if (e == ex) {
                int leader = __ffsll(m) - 1;
                int base = 0;
                if (lane == leader) base = atomicAdd(&meta[8 + ex], __popcll(m));
                base = __shfl(base, leader, 64);
                pos = meta[24 + ex] + base + __popcll(m & ((1ull << lane) - 1ull));
            }
        }
        entry_tok[pos] = n;
        pos_of[2 * n + j] = pos;
    }
}

// ---------------- transpose+convert weights: W[l][e][k][n] -> Wt[l][e][n][k] fp16 ----------------
__global__ __launch_bounds__(256)
void transpose_w(const float* __restrict__ W1, const float* __restrict__ W2,
                 const float* __restrict__ W3, _Float16* __restrict__ Wt)
{
    __shared__ float t[32][33];
    int mat = blockIdx.z;
    const float* src = (mat < 8) ? W1 + (size_t)mat * DIM * DIM
                     : (mat < 16) ? W2 + (size_t)(mat - 8) * DIM * DIM
                                  : W3 + (size_t)(mat - 16) * DIM * DIM;
    _Float16* dst = Wt + (size_t)mat * DIM * DIM;
    int tx = threadIdx.x & 31, ty = threadIdx.x >> 5;   // 32 x 8
    int x0 = blockIdx.x * 32, y0 = blockIdx.y * 32;     // x: n, y: k
#pragma unroll
    for (int j = 0; j < 4; j++)
        t[ty + 8 * j][tx] = src[(size_t)(y0 + ty + 8 * j) * DIM + x0 + tx];
    __syncthreads();
#pragma unroll
    for (int j = 0; j < 4; j++)
        dst[(size_t)(x0 + ty + 8 * j) * DIM + y0 + tx] = (_Float16)t[tx][ty + 8 * j];
}

// ---------------- fp16 MFMA GEMM: 64x128 tile, BK=64, dbuf LDS, 1 barrier/iter ----------------
// GATHER=1: A rows via entry_tok (layer 1); else contiguous gathered order.
template <int GATHER>
__global__ __launch_bounds__(256)
void gemm_mfma(const _Float16* __restrict__ A, const _Float16* __restrict__ Wt,
               const float* __restrict__ Bias, _Float16* __restrict__ Out,
               const int* __restrict__ meta, const int* __restrict__ tile_e,
               const int* __restrict__ tile_r, const int* __restrict__ entry_tok)
{
    int tile = blockIdx.y;
    if (tile >= meta[16]) return;
    int e = tile_e[tile];
    int row0 = tile_r[tile];
    int n0 = blockIdx.x * BN;

    // chunk = 16 rows x 32 k = 1024 B; lane l -> row (l&15), k-chunk (l>>4)*8.
    // sA[b]: chunks (kb*4 + g), g=row-group 0..3.  sB[b]: chunks (kb*8 + cg), cg 0..7.
    __shared__ _Float16 sA[2][BM * BK];   // 2 x 8 KB
    __shared__ _Float16 sB[2][BN * BK];   // 2 x 16 KB
    __shared__ int rtok[BM];

    int tid = threadIdx.x;
    int w = tid >> 6, l = tid & 63;
    int rlo = l & 15, kc = l >> 4;

    if (GATHER) {
        if (tid < BM) {
            int t = entry_tok[row0 + tid];
            rtok[tid] = (t < 0) ? 0 : t;    // pad slots hold poison (<0) -> token 0
        }
        __syncthreads();
    }

    const _Float16* Wb = Wt + (size_t)e * DIM * DIM;

    int arow;
    if (GATHER) arow = rtok[w * 16 + rlo];
    else        arow = row0 + w * 16 + rlo;
    const _Float16* asrc  = A  + (size_t)arow * DIM + kc * 8;                       // g = w
    const _Float16* bsrc0 = Wb + (size_t)(n0 + w * 16 + rlo) * DIM + kc * 8;        // cg = w
    const _Float16* bsrc1 = Wb + (size_t)(n0 + (w + 4) * 16 + rlo) * DIM + kc * 8;  // cg = w+4

    int mg = (w >> 1) * 2;   // A row-group base (2 groups/wave)
    int ng = (w & 1) * 4;    // B col-group base (4 groups/wave)

    f32x4 acc[2][4];
#pragma unroll
    for (int mi = 0; mi < 2; mi++)
#pragma unroll
        for (int ni = 0; ni < 4; ni++) acc[mi][ni] = (f32x4){0.f, 0.f, 0.f, 0.f};

    auto stage = [&](int b, int k0) {
        GLOAD_LDS16(asrc + k0,       &sA[b][(0 * 4 + w) * 512]);
        GLOAD_LDS16(asrc + k0 + 32,  &sA[b][(1 * 4 + w) * 512]);
        GLOAD_LDS16(bsrc0 + k0,      &sB[b][(0 * 8 + w) * 512]);
        GLOAD_LDS16(bsrc1 + k0,      &sB[b][(0 * 8 + w + 4) * 512]);
        GLOAD_LDS16(bsrc0 + k0 + 32, &sB[b][(1 * 8 + w) * 512]);
        GLOAD_LDS16(bsrc1 + k0 + 32, &sB[b][(1 * 8 + w + 4) * 512]);
    };

    auto compute = [&](int b) {
#pragma unroll
        for (int s = 0; s < 2; s++) {
            half8 af[2], bf[4];
#pragma unroll
            for (int mi = 0; mi < 2; mi++)
                af[mi] = *(const half8*)&sA[b][(s * 4 + mg + mi) * 512 + l * 8];
#pragma unroll
            for (int ni = 0; ni < 4; ni++)
                bf[ni] = *(const half8*)&sB[b][(s * 8 + ng + ni) * 512 + l * 8];
#pragma unroll
            for (int mi = 0; mi < 2; mi++)
#pragma unroll
                for (int ni = 0; ni < 4; ni++)
                    acc[mi][ni] = __builtin_amdgcn_mfma_f32_16x16x32_f16(af[mi], bf[ni], acc[mi][ni], 0, 0, 0);
        }
    };

    stage(0, 0);
    __syncthreads();                          // buf0 ready (compiler drains vmcnt)
    for (int it = 0; it < NIT; it++) {
        if (it + 1 < NIT) stage((it + 1) & 1, (it + 1) * BK);  // in flight during compute
        compute(it & 1);
        __syncthreads();                      // next buf ready; this buf free
    }

    // epilogue: C/D layout col=lane&15, row=(lane>>4)*4+reg
    int wm = (w >> 1) * 32, wn = (w & 1) * 64;
#pragma unroll
    for (int ni = 0; ni < 4; ni++) {
        int col = n0 + wn + ni * 16 + (l & 15);
        float b = Bias[e * DIM + col];
#pragma unroll
        for (int mi = 0; mi < 2; mi++) {
            int rbase = row0 + wm + mi * 16 + (l >> 4) * 4;
#pragma unroll
            for (int r = 0; r < 4; r++) {
                float v = fmaxf(acc[mi][ni][r] + b, 0.f);
                Out[(size_t)(rbase + r) * DIM + col] = (_Float16)v;
            }
        }
    }
}

// ---------------- combine: out[n] = w0*y[pos0] + w1*y[pos1] ----------------
__global__ __launch_bounds__(256)
void combine_kernel(const _Float16* __restrict__ y, const int* __restrict__ pos_of,
                    const float* __restrict__ top_w, float* __restrict__ out)
{
    int n = blockIdx.x * 4 + (threadIdx.x >> 6);
    int l = threadIdx.x & 63;
    int p0 = pos_of[2 * n], p1 = pos_of[2 * n + 1];
    float w0 = top_w[2 * n], w1 = top_w[2 * n + 1];
    half8 a = *(const half8*)(y + (size_t)p0 * DIM + l * 8);
    half8 b = *(const half8*)(y + (size_t)p1 * DIM + l * 8);
    float4 o0, o1;
    o0.x = w0 * (float)a[0] + w1 * (float)b[0];
    o0.y = w0 * (float)a[1] + w1 * (float)b[1];
    o0.z = w0 * (float)a[2] + w1 * (float)b[2];
    o0.w = w0 * (float)a[3] + w1 * (float)b[3];
    o1.x = w0 * (float)a[4] + w1 * (float)b[4];
    o1.y = w0 * (float)a[5] + w1 * (float)b[5];
    o1.z = w0 * (float)a[6] + w1 * (float)b[6];
    o1.w = w0 * (float)a[7] + w1 * (float)b[7];
    float* op = out + (size_t)n * DIM + l * 8;
    *(float4*)op = o0;
    *(float4*)(op + 4) = o1;
}

extern "C" void kernel_launch(void* const* d_in, const int* in_sizes, int n_in,
                              void* d_out, int out_size, void* d_ws, size_t ws_size,
                              hipStream_t stream)
{
    const float* x      = (const float*)d_in[0];
    const float* gate_w = (const float*)d_in[1];
    const float* gate_b = (const float*)d_in[2];
    const float* w1     = (const float*)d_in[3];
    const float* b1     = (const float*)d_in[4];
    const float* w2     = (const float*)d_in[5];
    const float* b2     = (const float*)d_in[6];
    const float* w3     = (const float*)d_in[7];
    const float* b3     = (const float*)d_in[8];
    float* out = (float*)d_out;

    char* ws = (char*)d_ws;
    int*      meta      = (int*)(ws + META_OFF);
    int*      tile_e    = (int*)(ws + TILE_E_OFF);
    int*      tile_r    = (int*)(ws + TILE_R_OFF);
    int*      top_e     = (int*)(ws + TOPE_OFF);
    float*    top_w     = (float*)(ws + TOPW_OFF);
    int*      pos_of    = (int*)(ws + POS_OFF);
    int*      entry_tok = (int*)(ws + ETOK_OFF);
    _Float16* xh        = (_Float16*)(ws + XH_OFF);
    _Float16* wt        = (_Float16*)(ws + WT_OFF);
    _Float16* h1        = (_Float16*)(ws + H1_OFF);
    _Float16* h2        = (_Float16*)(ws + H2_OFF);

    hipMemsetAsync(meta, 0, 256, stream);

    gate_kernel<<<NTOK / 4, 256, 0, stream>>>(x, gate_w, gate_b, top_e, top_w, xh, meta);
    scan_kernel<<<1, 64, 0, stream>>>(meta, tile_e, tile_r);
    scatter_kernel<<<NTOK / 256, 256, 0, stream>>>(top_e, meta, entry_tok, pos_of);
    transpose_w<<<dim3(16, 16, 24), 256, 0, stream>>>(w1, w2, w3, wt);

    _Float16* wt1 = wt;
    _Float16* wt2 = wt + (size_t)8 * DIM * DIM;
    _Float16* wt3 = wt + (size_t)16 * DIM * DIM;

    dim3 grid(DIM / BN, MAXT);
    gemm_mfma<1><<<grid, 256, 0, stream>>>(xh, wt1, b1, h1, meta, tile_e, tile_r, entry_tok);
    gemm_mfma<0><<<grid, 256, 0, stream>>>(h1, wt2, b2, h2, meta, tile_e, tile_r, entry_tok);
    gemm_mfma<0><<<grid, 256, 0, stream>>>(h2, wt3, b3, h1, meta, tile_e, tile_r, entry_tok);

    combine_kernel<<<NTOK / 4, 256, 0, stream>>>(h1, pos_of, top_w, out);
}